// Round 7
// baseline (14830.701 us; speedup 1.0000x reference)
//
#include <hip/hip_runtime.h>
#include <cmath>

#define B 128
#define T 128
#define H 512
#define TGT 32
#define SCOPE_AGENT __HIP_MEMORY_SCOPE_AGENT

// ws: dstate [2 parity][4 layer][B][H] f32 (2MB) | ctr 16KB | l0/G1 [T][B][1024] f32 (64MB)
struct Args {
  const float *x, *eWih0, *eWhh0, *eWih1, *eWhh1, *ebih, *ebhh;
  const float *dWih0, *dWihr, *dWhh, *dbih, *dbhh, *linW, *linb;
  float *dst; float *l0; unsigned *ctr; float *out;
};

__global__ void kinit(float* __restrict__ st, unsigned* __restrict__ ctr) {
  int idx = blockIdx.x * 256 + threadIdx.x;
  for (int i = idx; i < 4 * B * H; i += 65536) st[i] = 0.f;  // parity-0 state
  if (idx < 4096) ctr[idx] = 0u;
}

__device__ __forceinline__ float d4(float4 a, float4 b) {
  return a.x * b.x + a.y * b.y + a.z * b.z + a.w * b.w;
}
__device__ __forceinline__ void drain() {
  asm volatile("s_waitcnt vmcnt(0) lgkmcnt(0)" ::: "memory");
}
// coherent dword-pair load / dword store (device-scope relaxed atomics carry the
// cache-bypass bits; no acquire/release fences => no L2 inv/wb in the hot loop)
__device__ __forceinline__ void ld2(const float* p, float& a, float& b) {
  unsigned long long v = __hip_atomic_load((const unsigned long long*)p,
                                           __ATOMIC_RELAXED, SCOPE_AGENT);
  a = __uint_as_float((unsigned)v);
  b = __uint_as_float((unsigned)(v >> 32));
}
__device__ __forceinline__ void st1(float* p, float v) {
  __hip_atomic_store(p, v, __ATOMIC_RELAXED, SCOPE_AGENT);
}
__device__ __forceinline__ void bump_rel(unsigned* c) {
  drain();            // all sc-stores acked at coherence point
  __syncthreads();    // ... by every wave of the block
  if (threadIdx.x == 0) __hip_atomic_fetch_add(c, 1u, __ATOMIC_RELAXED, SCOPE_AGENT);
}
__device__ __forceinline__ void wait_at(unsigned* c, unsigned t) {
  if (threadIdx.x == 0)
    while (__hip_atomic_load(c, __ATOMIC_RELAXED, SCOPE_AGENT) < t)
      __builtin_amdgcn_s_sleep(1);
  __syncthreads();
}
// phase barrier WITH real fences (flushes ordinary data like l0) - only 3 uses
__device__ __forceinline__ void gridbar(unsigned* g, unsigned tgt) {
  __syncthreads();
  if (threadIdx.x == 0) {
    __hip_atomic_fetch_add(g, 1u, __ATOMIC_RELEASE, SCOPE_AGENT);
    while (__hip_atomic_load(g, __ATOMIC_RELAXED, SCOPE_AGENT) < tgt)
      __builtin_amdgcn_s_sleep(1);
    (void)__hip_atomic_load(g, __ATOMIC_ACQUIRE, SCOPE_AGENT);
  }
  __syncthreads();
}

// ===========================================================================
// Encoder phase. 32 groups x 8 blocks (bx = j*32 + g => group-mates share
// bx%8 == g%8 -> same XCD heuristically). Group owns 8 chains (4 batches x 2
// dirs). Block j covers n-slice [64j,64j+64); full K=512 per block (no
// cross-block reduce). Weights register-resident (2 dirs x 2 n x 16 float4).
// ===========================================================================
template <bool E0P>
__device__ void enc_phase(const Args& a, int bx, int tid) {
  const int j = bx >> 5, g = bx & 31;
  const int u = tid >> 3, kq = tid & 7;     // u in [0,32), kq in [0,8): 64-k slice
  const int nA = 64 * j + u, nB = nA + 32;
  const int k0 = kq * 64;
  const float* WHH = E0P ? a.eWhh0 : a.eWhh1;
  const int L0 = E0P ? 0 : 2;
  unsigned* ctr = a.ctr + g * 32;
  const unsigned base = E0P ? 0u : 1024u;   // shared counter continues into E1

  float4 wA[2][16], wB[2][16];
#pragma unroll
  for (int d = 0; d < 2; d++) {
    const float4* pa = (const float4*)(WHH + ((size_t)d * H + nA) * H + k0);
    const float4* pb = (const float4*)(WHH + ((size_t)d * H + nB) * H + k0);
#pragma unroll
    for (int i = 0; i < 16; i++) { wA[d][i] = pa[i]; wB[d][i] = pb[i]; }
  }
  float bsA[2], bsB[2], wxA[2][3], wxB[2][3];
  if (E0P) {
#pragma unroll
    for (int d = 0; d < 2; d++) {
      bsA[d] = a.ebih[d * H + nA] + a.ebhh[d * H + nA];
      bsB[d] = a.ebih[d * H + nB] + a.ebhh[d * H + nB];
#pragma unroll
      for (int i = 0; i < 3; i++) {
        wxA[d][i] = a.eWih0[((size_t)d * H + nA) * 3 + i];
        wxB[d][i] = a.eWih0[((size_t)d * H + nB) * 3 + i];
      }
    }
  }

  for (int s = 0; s < T; s++) {
    wait_at(ctr, base + 8u * (unsigned)s);
    const int p = s & 1, q = 1 - p;
#pragma unroll
    for (int dir = 0; dir < 2; dir++) {
      const int t = dir ? (T - 1 - s) : s;
      for (int cb = 0; cb < 4; cb++) {
        const int b = g * 4 + cb;
        const float* hsrc = a.dst + ((size_t)(p * 4 + L0 + dir) * B + b) * H + k0;
        float aA = 0.f, aB = 0.f;
#pragma unroll
        for (int half = 0; half < 2; half++) {
          float hv[32];
#pragma unroll
          for (int i2 = 0; i2 < 16; i2++)
            ld2(hsrc + half * 32 + 2 * i2, hv[2 * i2], hv[2 * i2 + 1]);
#pragma unroll
          for (int i = 0; i < 8; i++) {
            float4 wa = wA[dir][half * 8 + i], wb = wB[dir][half * 8 + i];
            int o = 4 * i;
            aA += wa.x * hv[o] + wa.y * hv[o + 1] + wa.z * hv[o + 2] + wa.w * hv[o + 3];
            aB += wb.x * hv[o] + wb.y * hv[o + 1] + wb.z * hv[o + 2] + wb.w * hv[o + 3];
          }
        }
        aA += __shfl_xor(aA, 4); aA += __shfl_xor(aA, 2); aA += __shfl_xor(aA, 1);
        aB += __shfl_xor(aB, 4); aB += __shfl_xor(aB, 2); aB += __shfl_xor(aB, 1);
        if (kq == 0) {
          float preA, preB;
          if (E0P) {
            const float* xr = a.x + ((size_t)b * T + t) * 3;
            float x0 = xr[0], x1 = xr[1], x2 = xr[2];
            preA = aA + bsA[dir] + x0 * wxA[dir][0] + x1 * wxA[dir][1] + x2 * wxA[dir][2];
            preB = aB + bsB[dir] + x0 * wxB[dir][0] + x1 * wxB[dir][1] + x2 * wxB[dir][2];
          } else {
            const float* g1 = a.l0 + ((size_t)t * B + b) * 1024 + dir * 512;
            preA = aA + g1[nA];   // G1 already holds proj + biases
            preB = aB + g1[nB];
          }
          float oA = tanhf(preA), oB = tanhf(preB);
          float* hd = a.dst + ((size_t)(q * 4 + L0 + dir) * B + b) * H;
          st1(hd + nA, oA);
          st1(hd + nB, oB);
          if (E0P) {
            float* lr = a.l0 + ((size_t)t * B + b) * 1024 + dir * 512;
            lr[nA] = oA;  lr[nB] = oB;   // ordinary; flushed at phase barrier
          }
        }
      }
    }
    bump_rel(ctr);
  }
}

// ===========================================================================
// enc1 input projection, in-place over l0 (adds layer-1 biases). Round-6
// verified logic (sm now big enough for the 33088-float footprint).
// ===========================================================================
__device__ void proj_phase(const Args& a, float* sm, int bx, int tid) {
  const int r0 = bx * 64;
  const int rg = tid >> 4, cg = tid & 15;
  for (int hh = 0; hh < 2; hh++) {
    const int rbase = r0 + hh * 32;
    __syncthreads();
    {
      int row = tid >> 3, seg = tid & 7;
      const float4* gp = (const float4*)(a.l0 + (size_t)(rbase + row) * 1024 + seg * 128);
      float4* lp = (float4*)(sm + row * 1032 + seg * 128);
#pragma unroll
      for (int i = 0; i < 32; i++) lp[i] = gp[i];
    }
    __syncthreads();
    const float4* x0 = (const float4*)(sm + (rg * 2 + 0) * 1032);
    const float4* x1 = (const float4*)(sm + (rg * 2 + 1) * 1032);
    for (int jj = 0; jj < 8; jj++) {
      const int c0 = jj * 128 + cg * 8;
      float acc0[8], acc1[8];
#pragma unroll
      for (int i = 0; i < 8; i++) { acc0[i] = 0.f; acc1[i] = 0.f; }
      const float4* w0 = (const float4*)(a.eWih1 + (size_t)c0 * 1024);
      for (int k4 = 0; k4 < 256; k4++) {
        float4 xv0 = x0[k4], xv1 = x1[k4];
#pragma unroll
        for (int cc = 0; cc < 8; cc++) {
          float4 wv = w0[cc * 256 + k4];
          acc0[cc] += d4(wv, xv0);
          acc1[cc] += d4(wv, xv1);
        }
      }
#pragma unroll
      for (int cc = 0; cc < 8; cc++) {
        int c = c0 + cc;
        float bias = a.ebih[1024 + c] + a.ebhh[1024 + c];
        a.l0[(size_t)(rbase + rg * 2 + 0) * 1024 + c] = acc0[cc] + bias;
        a.l0[(size_t)(rbase + rg * 2 + 1) * 1024 + c] = acc1[cc] + bias;
      }
    }
  }
}

// ===========================================================================
// Decoder: 4 groups (g = bx&3, 32 batches) x 64 blocks (j = bx>>2, 8 n).
// All-layer weights register-resident (28 float4/thread). h staged via
// coherent loads into 36-swizzled LDS; PART reduce at stride 65 (2-way=free).
// ===========================================================================
__device__ void dec_phase(const Args& a, float* sm, int bx, int tid) {
  const int j = bx >> 2, g = bx & 3;
  const int n0 = 8 * j, b0 = 32 * g;
  const int n2 = tid >> 6, kq = tid & 63;   // FMA: n pair (n0+n2, n0+4+n2), k-slice
  const int n_a = n0 + n2, n_b = n0 + 4 + n2;
  const int hb = tid >> 3, l8 = tid & 7;    // head / reduce roles
  unsigned* ctr = a.ctr + (32 + g) * 32;
  float* HOLD = sm;            // 32*576
  float* HIN  = sm + 18432;    // 32*576  (PART overlays after FMA)
  float* PART = sm + 18432;    // 256*65 = 16640
  float* XIN  = sm + 36864;    // 32*4

  float4 W0a[2], W0b[2], Wa[3][4], Wb[3][4];
  {
    const float4* p;
    p = (const float4*)(a.dWhh + (size_t)n_a * H + kq * 8);
    W0a[0] = p[0]; W0a[1] = p[1];
    p = (const float4*)(a.dWhh + (size_t)n_b * H + kq * 8);
    W0b[0] = p[0]; W0b[1] = p[1];
#pragma unroll
    for (int l = 1; l < 4; l++) {
      const float* sa = (kq < 32) ? (a.dWihr + ((size_t)(l - 1) * H + n_a) * H + kq * 16)
                                  : (a.dWhh + ((size_t)l * H + n_a) * H + (kq - 32) * 16);
      const float* sb = (kq < 32) ? (a.dWihr + ((size_t)(l - 1) * H + n_b) * H + kq * 16)
                                  : (a.dWhh + ((size_t)l * H + n_b) * H + (kq - 32) * 16);
#pragma unroll
      for (int i = 0; i < 4; i++) {
        Wa[l - 1][i] = ((const float4*)sa)[i];
        Wb[l - 1][i] = ((const float4*)sb)[i];
      }
    }
  }
  float bsl[4];
#pragma unroll
  for (int l = 0; l < 4; l++)
    bsl[l] = a.dbih[l * H + n0 + (tid & 7)] + a.dbhh[l * H + n0 + (tid & 7)];
  float wx0 = a.dWih0[(n0 + (tid & 7)) * 3 + 0];
  float wx1 = a.dWih0[(n0 + (tid & 7)) * 3 + 1];
  float wx2 = a.dWih0[(n0 + (tid & 7)) * 3 + 2];
  float4 LW[16];
  {
    const float4* lp = (const float4*)(a.linW + l8 * 64);
#pragma unroll
    for (int i = 0; i < 16; i++) LW[i] = lp[i];
  }
  float lb = a.linb[0];
  if (tid < 32) {
    const float* xr = a.x + ((size_t)(b0 + tid) * T + (T - 1)) * 3;
    XIN[tid * 4 + 0] = xr[0]; XIN[tid * 4 + 1] = xr[1];
    XIN[tid * 4 + 2] = xr[2]; XIN[tid * 4 + 3] = 0.f;
  }

  for (int m = 0; m < 128; m++) {
    const int s = m >> 2, l = m & 3;
    const int p = s & 1, q = 1 - p;
    if (m) wait_at(ctr, 64u * (unsigned)m);

    // stage HOLD (= dst[p][l]) and, for l>=1, HIN (= dst[q][l-1])
    {
      const float* srcH = a.dst + ((size_t)(p * 4 + l) * B + b0) * H;
      const float* srcI = (l > 0) ? (a.dst + ((size_t)(q * 4 + (l - 1)) * B + b0) * H) : nullptr;
      for (int it = 0; it < 32; it++) {
        int f = it * 256 + tid;          // ull index in [0,8192)
        int bq = f >> 8;
        int k2 = (f & 255) * 2;
        int off = bq * 576 + (k2 >> 5) * 36 + (k2 & 31);
        float x0, x1;
        ld2(srcH + (size_t)bq * H + k2, x0, x1);
        HOLD[off] = x0; HOLD[off + 1] = x1;
        if (srcI) {
          ld2(srcI + (size_t)bq * H + k2, x0, x1);
          HIN[off] = x0; HIN[off + 1] = x1;
        }
      }
    }
    // head (o0 / xin recurrence) from global h3 = dst[p][3]
    if (l == 0 && s > 0) {
      const float* h3 = a.dst + ((size_t)(p * 4 + 3) * B + (b0 + hb)) * H + l8 * 64;
      float v = 0.f;
#pragma unroll
      for (int i = 0; i < 16; i++) {
        float h0, h1, h2, h3v;
        ld2(h3 + 4 * i, h0, h1);
        ld2(h3 + 4 * i + 2, h2, h3v);
        float4 w = LW[i];
        v += w.x * h0 + w.y * h1 + w.z * h2 + w.w * h3v;
      }
      v += __shfl_xor(v, 4); v += __shfl_xor(v, 2); v += __shfl_xor(v, 1);
      if (l8 == 0) {
        float o0 = v + lb;
        float s1v = XIN[hb * 4 + 0] - o0;
        float s2v = XIN[hb * 4 + 1] - s1v;
        XIN[hb * 4 + 0] = o0; XIN[hb * 4 + 1] = s1v; XIN[hb * 4 + 2] = s2v;
        if (j == 0) a.out[(size_t)(b0 + hb) * TGT + (s - 1)] = o0;
      }
    }
    __syncthreads();

    float va[32], vb[32];
    if (l == 0) {
      const float* hp = HOLD + (kq >> 2) * 36 + (kq & 3) * 8;
#pragma unroll 8
      for (int b = 0; b < 32; b++) {
        const float4* h4 = (const float4*)(hp + b * 576);
        float4 h0 = h4[0], h1 = h4[1];
        va[b] = d4(W0a[0], h0) + d4(W0a[1], h1);
        vb[b] = d4(W0b[0], h0) + d4(W0b[1], h1);
      }
    } else {
      const float* base = (kq < 32) ? HIN : HOLD;
      const float* hp = base + ((kq & 31) >> 1) * 36 + (kq & 1) * 16;
      const int li = l - 1;
      float4 A0 = Wa[li][0], A1 = Wa[li][1], A2 = Wa[li][2], A3 = Wa[li][3];
      float4 B0 = Wb[li][0], B1 = Wb[li][1], B2 = Wb[li][2], B3 = Wb[li][3];
#pragma unroll 8
      for (int b = 0; b < 32; b++) {
        const float4* h4 = (const float4*)(hp + b * 576);
        float4 h0 = h4[0], h1 = h4[1], h2 = h4[2], h3v = h4[3];
        va[b] = d4(A0, h0) + d4(A1, h1) + d4(A2, h2) + d4(A3, h3v);
        vb[b] = d4(B0, h0) + d4(B1, h1) + d4(B2, h2) + d4(B3, h3v);
      }
    }
    __syncthreads();   // HIN reads done -> PART may overlay
#pragma unroll 8
    for (int b = 0; b < 32; b++) {
      PART[(b * 8 + n2) * 65 + kq] = va[b];
      PART[(b * 8 + 4 + n2) * 65 + kq] = vb[b];
    }
    __syncthreads();
    {
      const float* pr = PART + tid * 65;
      float sum = 0.f;
#pragma unroll
      for (int i = 0; i < 64; i++) sum += pr[i];
      float pre = sum + bsl[l];
      if (l == 0)
        pre += XIN[hb * 4 + 0] * wx0 + XIN[hb * 4 + 1] * wx1 + XIN[hb * 4 + 2] * wx2;
      float o = tanhf(pre);
      st1(a.dst + ((size_t)(q * 4 + l) * B + (b0 + hb)) * H + (n0 + l8), o);
    }
    bump_rel(ctr);
  }

  if (j == 0) {   // final output column 31 from dst[0][3]
    wait_at(ctr, 64u * 128u);
    const float* h3 = a.dst + ((size_t)(0 * 4 + 3) * B + (b0 + hb)) * H + l8 * 64;
    float v = 0.f;
#pragma unroll
    for (int i = 0; i < 16; i++) {
      float h0, h1, h2, h3v;
      ld2(h3 + 4 * i, h0, h1);
      ld2(h3 + 4 * i + 2, h2, h3v);
      float4 w = LW[i];
      v += w.x * h0 + w.y * h1 + w.z * h2 + w.w * h3v;
    }
    v += __shfl_xor(v, 4); v += __shfl_xor(v, 2); v += __shfl_xor(v, 1);
    if (l8 == 0) a.out[(size_t)(b0 + hb) * TGT + 31] = v + lb;
  }
}

// ===========================================================================
__global__ __launch_bounds__(256, 1) void birnn_all(Args a) {
  __shared__ __align__(16) float sm[36992];   // 147968 B -> 1 block/CU
  const int tid = threadIdx.x, bx = blockIdx.x;
  enc_phase<true>(a, bx, tid);                 // E0
  gridbar(a.ctr + 40 * 32, 256u);
  proj_phase(a, sm, bx, tid);
  gridbar(a.ctr + 40 * 32, 512u);
  enc_phase<false>(a, bx, tid);                // E1
  gridbar(a.ctr + 40 * 32, 768u);
  dec_phase(a, sm, bx, tid);
}

// ---------------------------------------------------------------------------
extern "C" void kernel_launch(void* const* d_in, const int* in_sizes, int n_in,
                              void* d_out, int out_size, void* d_ws, size_t ws_size,
                              hipStream_t stream) {
  float* dst = (float*)d_ws;
  unsigned* ctr = (unsigned*)((char*)d_ws + 2097152);
  float* l0 = (float*)((char*)d_ws + 2097152 + 16384);

  kinit<<<256, 256, 0, stream>>>(dst, ctr);

  Args args;
  args.x = (const float*)d_in[0];
  args.eWih0 = (const float*)d_in[2];
  args.eWhh0 = (const float*)d_in[3];
  args.eWih1 = (const float*)d_in[4];
  args.eWhh1 = (const float*)d_in[5];
  args.ebih = (const float*)d_in[6];
  args.ebhh = (const float*)d_in[7];
  args.dWih0 = (const float*)d_in[8];
  args.dWihr = (const float*)d_in[9];
  args.dWhh = (const float*)d_in[10];
  args.dbih = (const float*)d_in[11];
  args.dbhh = (const float*)d_in[12];
  args.linW = (const float*)d_in[13];
  args.linb = (const float*)d_in[14];
  args.dst = dst; args.l0 = l0; args.ctr = ctr;
  args.out = (float*)d_out;

  void* kp[] = { &args };
  hipError_t err = hipLaunchCooperativeKernel((void*)birnn_all, dim3(256), dim3(256),
                                              kp, 0, stream);
  if (err != hipSuccess) {
    // raw device-scope atomics only; 148KB LDS forces 1 block/CU so all 256
    // blocks co-reside on 256 CUs even without cooperative launch.
    birnn_all<<<dim3(256), dim3(256), 0, stream>>>(args);
  }
}